// Round 1
// baseline (80.952 us; speedup 1.0000x reference)
//
#include <hip/hip_runtime.h>
#include <math.h>

#define TH 512                      // 8 waves/block (R17 optimum kept)
#define QPB 256                     // R19: WT=1 -> 8 waves x 32 queries
#define SEGS 8                      // db segments (grid.y)
#define SCH 32                      // chunks (32 db pts each) per LDS stage
#define PPT ((SCH * 32) / TH)       // staged points per thread per stage = 2
#define POISON 0xAAAAAAAAu

typedef __bf16 bf16x8 __attribute__((ext_vector_type(8)));
typedef float  f32x16 __attribute__((ext_vector_type(16)));

// R19 theory: R17's WT=2 left no VGPRs for cross-iteration MFMA results ->
// each wave serialized  issue-4-MFMA -> wait latency -> 32 min3.  Matrix pipe
// ~20% busy (33us vs 6.8us floor).  Fix: WT=1 + explicit 1-deep SW pipeline
// (min3 of pair i-1 between the two MFMAs of pair i), double-buffered LDS
// (one barrier/stage), and early-issued global loads (T14).  Fragment math,
// C/D layout, epilogue and reduce kernel are verbatim from validated R17.
//
// Split-bf16 MFMA 32x32x16, db on A / queries on B (R15-validated):
//  kg = lane>>5; A row = db idx = lane&31; B col = query idx = lane&31.
//  kg0 (k0-7):  A(db)={th(x,y,z), th(x,y,z), 1, 1}
//               B(q) ={-qh(x,y,z), -ql(x,y,z), q2h_hi, q2h_lo}
//  kg1 (k8-15): A(db)={tl(x,y,z), t2h_hi, t2h_lo, tl(x,y,z)}
//               B(q) ={-qh(x,y,z), 1, 1, -ql(x,y,z)}
//  => D = ||q||^2/2 + ||t||^2/2 - q.t = sq_dist/2
// C/D: col = query = lane&31, row = db = (e&3)+8*(e>>2)+4*kg  [m74/m101].
//
// REG BUDGET: 4 waves/EU -> 128 unified VGPR+AGPR cap.  Hot-loop live set:
// rmin 16 + zf 16 + qfr 4 + dP/dN window 48 + aCur/aNext 16 + stage-held
// loads 6 + addr ~10 = ~118.  min3 placed BETWEEN the two MFMAs keeps the
// d-window at 48 (not 64).
__global__ __launch_bounds__(TH, 4) void chamfer_mfma_kernel(
        const float* __restrict__ pred, int n,
        const float* __restrict__ target, int m,
        float* __restrict__ partF, float* __restrict__ partB) {
    const int dir = blockIdx.z;
    const float* __restrict__ q  = dir ? target : pred;
    const float* __restrict__ db = dir ? pred : target;
    const int nq  = dir ? m : n;
    const int ndb = dir ? n : m;
    float* __restrict__ outPart = dir ? partB : partF;

    const int tid  = threadIdx.x;
    const int lane = tid & 63;
    const int wave = tid >> 6;         // 0..7
    const int kg   = lane >> 5;        // k-group 0..1
    const int rc   = lane & 31;        // A db-row / B query-col
    const __bf16 one = (__bf16)1.0f;

    // ---- Query fragment (B operand, once per block; WT=1) ----
    const int qtb = blockIdx.x * QPB + wave * 32;
    const int qi0 = qtb + rc;
    {
    }
    bf16x8 qfr;
    {
        int qc = (qi0 < nq) ? qi0 : 0;            // clamp; OOB never stored
        float qx = -q[qc * 3 + 0], qy = -q[qc * 3 + 1], qz = -q[qc * 3 + 2];
        __bf16 xh = (__bf16)qx; __bf16 xl = (__bf16)(qx - (float)xh);
        __bf16 yh = (__bf16)qy; __bf16 yl = (__bf16)(qy - (float)yh);
        __bf16 zh = (__bf16)qz; __bf16 zl = (__bf16)(qz - (float)zh);
        float q2h = 0.5f * fmaf(qz, qz, fmaf(qy, qy, qx * qx));
        __bf16 hh = (__bf16)q2h; __bf16 hl = (__bf16)(q2h - (float)hh);
        bf16x8 b0 = {xh, yh, zh, xl, yl, zl, hh, hl};
        bf16x8 b1 = {xh, yh, zh, one, one, xl, yl, zl};
        qfr = kg ? b1 : b0;
    }
    f32x16 rmin = 3.0e38f;
    asm("" : "+v"(rmin));              // pin min-chain to arch VGPRs
    f32x16 zf = 0.0f;
    asm("" : "+v"(zf));                // pin C operand -> VGPR-form MFMA

    // ---- db segment ----
    const int nchunks = (ndb + 31) >> 5;          // 32-pt chunks
    const int cpseg = (nchunks + SEGS - 1) / SEGS;
    const int c_begin = blockIdx.y * cpseg;
    const int c_end = min(nchunks, c_begin + cpseg);

    // Double-buffered: [buf(2)][chunk][kg(2)][row(32)] uint4.  Lane reads
    // sb[c*64 + lane]: 64 lanes x 16B fully linear = conflict-free b128.
    __shared__ uint4 sB[2 * SCH * 64];            // 64 KB

    // T14 split: global loads issued early, held in regs, converted late.
    float lx[PPT], ly[PPT], lz[PPT];

    auto issue = [&](int c0n) {
        const bool any = (c0n < c_end);
        const int lim = any ? min(SCH, c_end - c0n) * 32 : 0;
#pragma unroll
        for (int k = 0; k < PPT; ++k) {
            const int pl = tid + k * TH;
            const int gp = c0n * 32 + pl;
            float x = 0.f, y = 0.f, z = 0.f;
            if (pl < lim && gp < ndb) {
                x = db[gp * 3 + 0]; y = db[gp * 3 + 1]; z = db[gp * 3 + 2];
            }
            lx[k] = x; ly[k] = y; lz[k] = z;
        }
    };

    auto convert = [&](int c0, int csub, int bufb) {
        uint4* __restrict__ sw = &sB[bufb * (SCH * 64)];
#pragma unroll
        for (int k = 0; k < PPT; ++k) {
            const int pl = tid + k * TH;
            if (pl < csub * 32) {
                const int gp = c0 * 32 + pl;
                float tx = lx[k], ty = ly[k], tz = lz[k];
                float h = 1.0e30f;
                if (gp < ndb) h = 0.5f * fmaf(tz, tz, fmaf(ty, ty, tx * tx));
                __bf16 xh = (__bf16)tx; __bf16 xl = (__bf16)(tx - (float)xh);
                __bf16 yh = (__bf16)ty; __bf16 yl = (__bf16)(ty - (float)yh);
                __bf16 zh = (__bf16)tz; __bf16 zl = (__bf16)(tz - (float)zh);
                __bf16 hh = (__bf16)h;  __bf16 hl = (__bf16)(h - (float)hh);
                bf16x8 a0 = {xh, yh, zh, xh, yh, zh, one, one};
                bf16x8 a1 = {xl, yl, zl, hh, hl, xl, yl, zl};
                int ch = pl >> 5, cp = pl & 31;
                sw[ch * 64 + cp]      = __builtin_bit_cast(uint4, a0);
                sw[ch * 64 + 32 + cp] = __builtin_bit_cast(uint4, a1);
            }
        }
    };

#define MFMA_(A) __builtin_amdgcn_mfma_f32_32x32x16_bf16((A), qfr, zf, 0, 0, 0)
#define MIN3P()  do { _Pragma("unroll")                                       \
        for (int e = 0; e < 16; ++e)                                          \
            rmin[e] = fminf(fminf(rmin[e], dP0[e]), dP1[e]); } while (0)

    int buf = 0;
    issue(c_begin);                    // stage-0 loads in flight
    for (int c0 = c_begin; c0 < c_end; c0 += SCH, buf ^= 1) {
        const int csub = min(SCH, c_end - c0);
        convert(c0, csub, buf);        // write this stage (other buf is live
        issue(c0 + SCH);               //   for readers of stage-1: no WAR)
        __syncthreads();               // ONE barrier per stage

        const uint4* __restrict__ sb = &sB[buf * (SCH * 64)];
        const int NP = csub >> 1;      // chunk pairs

        if (NP > 0) {
            // prologue: pair 0 compute, pair 1 read
            bf16x8 aA = __builtin_bit_cast(bf16x8, sb[lane]);
            bf16x8 aB = __builtin_bit_cast(bf16x8, sb[64 + lane]);
            f32x16 dP0 = MFMA_(aA); asm("" : "+v"(dP0));
            f32x16 dP1 = MFMA_(aB); asm("" : "+v"(dP1));
            if (NP > 1) {
                aA = __builtin_bit_cast(bf16x8, sb[128 + lane]);
                aB = __builtin_bit_cast(bf16x8, sb[192 + lane]);
            }
            // steady state: read pair p+1, MFMA pair p, min3 pair p-1.
            // min3 block BETWEEN the two MFMAs: caps d-window at 48 regs
            // and gives the wave VALU work while the matrix pipe fills.
#pragma unroll 2
            for (int p = 1; p + 1 < NP; ++p) {
                bf16x8 nA = __builtin_bit_cast(bf16x8, sb[(p + 1) * 128 + lane]);
                bf16x8 nB = __builtin_bit_cast(bf16x8, sb[(p + 1) * 128 + 64 + lane]);
                f32x16 dN0 = MFMA_(aA); asm("" : "+v"(dN0));
                MIN3P();
                f32x16 dN1 = MFMA_(aB); asm("" : "+v"(dN1));
                dP0 = dN0; dP1 = dN1; aA = nA; aB = nB;
            }
            if (NP > 1) {              // last pair (no further read)
                f32x16 dN0 = MFMA_(aA); asm("" : "+v"(dN0));
                MIN3P();
                f32x16 dN1 = MFMA_(aB); asm("" : "+v"(dN1));
                dP0 = dN0; dP1 = dN1;
            }
            MIN3P();                   // drain
        }
        if (csub & 1) {                // odd tail chunk (not hit at 16384)
            bf16x8 tA = __builtin_bit_cast(bf16x8, sb[(csub - 1) * 64 + lane]);
            f32x16 d0 = MFMA_(tA); asm("" : "+v"(d0));
            rmin = __builtin_elementwise_min(rmin, d0);
        }
    }
#undef MFMA_
#undef MIN3P

    // ---- Epilogue: rows are db -> 15 in-lane mins + 1 shfl_xor(32) ----
    {
        f32x16 r = rmin;
        float v = r[0];
#pragma unroll
        for (int e = 1; e < 16; ++e) v = fminf(v, r[e]);
        v = fminf(v, __shfl_xor(v, 32, 64));       // combine kg halves
        if (kg == 0 && qi0 < nq)                   // 32 coalesced stores/tile
            outPart[(size_t)blockIdx.y * nq + qi0] = fmaxf(0.0f, v);
    }
}

// Fused reduce: 128 blocks; thread j owns one query: min over SEGS partials,
// sqrt(2*v), block-sum -> partials[b]; poison-aware last block finalizes.
__global__ __launch_bounds__(256) void reduce_kernel(
        const float* __restrict__ partF, const float* __restrict__ partB,
        float* __restrict__ partials, unsigned* __restrict__ counter,
        int n, int m, float* __restrict__ out, int nblocks) {
    const int tid = threadIdx.x;
    const int j = blockIdx.x * 256 + tid;        // flat query id in [0, n+m)
    const bool isF = j < n;
    const float* __restrict__ part = isF ? partF : partB;
    const int qn = isF ? n : m;
    const int qi = isF ? j : j - n;

    float v = 3.0e38f;
#pragma unroll
    for (int s = 0; s < SEGS; ++s)
        v = fminf(v, part[(size_t)s * qn + qi]);
    v = sqrtf(2.0f * fmaxf(0.0f, v));

    for (int off = 32; off > 0; off >>= 1) v += __shfl_down(v, off, 64);
    __shared__ float w[4];
    __shared__ unsigned s_last;
    int lane = tid & 63, wv = tid >> 6;
    if (lane == 0) w[wv] = v;
    __syncthreads();
    if (tid == 0) {
        partials[blockIdx.x] = w[0] + w[1] + w[2] + w[3];
        __threadfence();
        unsigned done = atomicAdd(counter, 1u);
        unsigned nb1 = (unsigned)(nblocks - 1);
        s_last = (done == nb1) || (done == POISON + nb1);
    }
    __syncthreads();
    if (!s_last) return;
    __threadfence();                   // acquire side

    // partials[0..63] = F blocks, [64..127] = B blocks. wave0 sums F, wave1 B.
    float p = 0.0f;
    if (tid < 128)
        p = __uint_as_float(__hip_atomic_load(
                (const unsigned*)&partials[tid],
                __ATOMIC_RELAXED, __HIP_MEMORY_SCOPE_AGENT));
    for (int off = 32; off > 0; off >>= 1) p += __shfl_down(p, off, 64);
    __shared__ float w2[2];
    if (tid == 0)  w2[0] = p;
    if (tid == 64) w2[1] = p;
    __syncthreads();
    if (tid == 0)
        out[0] = 0.5f * (w2[0] / (float)n + w2[1] / (float)m);
}

extern "C" void kernel_launch(void* const* d_in, const int* in_sizes, int n_in,
                              void* d_out, int out_size, void* d_ws, size_t ws_size,
                              hipStream_t stream) {
    const float* pred   = (const float*)d_in[0];
    const float* target = (const float*)d_in[1];
    const int n = in_sizes[0] / 3;   // 16384
    const int m = in_sizes[1] / 3;   // 16384

    float* partF = (float*)d_ws;                  // SEGS*n floats
    float* partB = partF + (size_t)SEGS * n;      // SEGS*m floats
    float* partials = partB + (size_t)SEGS * m;   // 128 floats
    unsigned* counter = (unsigned*)(partials + 128);
    float* out = (float*)d_out;

    int nmax = (n > m) ? n : m;
    int gx = (nmax + QPB - 1) / QPB;         // 64
    dim3 grid(gx, SEGS, 2);                  // 1024 blocks -> 2 resident/CU
    chamfer_mfma_kernel<<<grid, TH, 0, stream>>>(pred, n, target, m, partF, partB);

    int nb = (n + m) / 256;                  // 128; F in [0,64), B in [64,128)
    reduce_kernel<<<nb, 256, 0, stream>>>(partF, partB, partials, counter,
                                          n, m, out, nb);
}

// Round 2
// 77.451 us; speedup vs baseline: 1.0452x; 1.0452x over previous
//
#include <hip/hip_runtime.h>
#include <math.h>

#define TH 512                      // 8 waves/block
#define WT 4                        // R20: 4 query tiles/wave (was 2)
#define QPB (8 * WT * 32)           // 1024 queries per block
#define SEGS 8                      // db segments (grid.y)
#define SCH 64                      // chunks per LDS stage = whole segment
#define POISON 0xAAAAAAAAu

typedef __bf16 bf16x8 __attribute__((ext_vector_type(8)));
typedef float  f32x16 __attribute__((ext_vector_type(16)));

// R20 post-mortem of R19 (WT=1 SW-pipeline, 81us REGRESSION): A-fragment
// ds_read is 1KB per wave-MFMA amortized only over WT -> R19 DOUBLED LDS
// traffic (2MB/CU, 9.8us floor).  Lever points the other way: WT=4 at
// 2 waves/SIMD (256-VGPR cap).  LDS/MFMA halves vs R17 (0.25KB/MFMA,
// 2.45us floor), 8 independent MFMAs per pair-iter (lag-1 min3 placement
// keeps 4 in flight), segment single-staged in 64KB LDS (2 barriers/block),
// grid 256 = exactly 1 block/CU, one round.
//
// Split-bf16 MFMA 32x32x16, db on A / queries on B (R15-validated):
//  kg = lane>>5; A row = db idx = lane&31; B col = query idx = lane&31.
//  kg0 (k0-7):  A(db)={th(x,y,z), th(x,y,z), 1, 1}
//               B(q) ={-qh(x,y,z), -ql(x,y,z), q2h_hi, q2h_lo}
//  kg1 (k8-15): A(db)={tl(x,y,z), t2h_hi, t2h_lo, tl(x,y,z)}
//               B(q) ={-qh(x,y,z), 1, 1, -ql(x,y,z)}
//  => D = ||q||^2/2 + ||t||^2/2 - q.t = sq_dist/2
// C/D: col = query = lane&31, row = db = (e&3)+8*(e>>2)+4*kg  [m74/m101].
//
// REG BUDGET (2 waves/EU -> 256 cap): rmin 64 + qfr 16 + zf 16 + d-window
// 64 + aA/aB 8 + addr/stage ~25 = ~190.
__global__ __launch_bounds__(TH, 2) void chamfer_mfma_kernel(
        const float* __restrict__ pred, int n,
        const float* __restrict__ target, int m,
        float* __restrict__ partF, float* __restrict__ partB) {
    const int dir = blockIdx.z;
    const float* __restrict__ q  = dir ? target : pred;
    const float* __restrict__ db = dir ? pred : target;
    const int nq  = dir ? m : n;
    const int ndb = dir ? n : m;
    float* __restrict__ outPart = dir ? partB : partF;

    const int tid  = threadIdx.x;
    const int lane = tid & 63;
    const int wave = tid >> 6;         // 0..7
    const int kg   = lane >> 5;        // k-group 0..1
    const int rc   = lane & 31;        // A db-row / B query-col
    const __bf16 one = (__bf16)1.0f;

    // ---- Query fragments (B operand, once per block) ----
    bf16x8 qfr[WT];
    f32x16 rmin[WT];
    const int qtb = blockIdx.x * QPB + wave * (WT * 32);
#pragma unroll
    for (int t = 0; t < WT; ++t) {
        int qi = qtb + t * 32 + rc;
        int qc = (qi < nq) ? qi : 0;              // clamp; OOB never stored
        float qx = -q[qc * 3 + 0], qy = -q[qc * 3 + 1], qz = -q[qc * 3 + 2];
        __bf16 xh = (__bf16)qx; __bf16 xl = (__bf16)(qx - (float)xh);
        __bf16 yh = (__bf16)qy; __bf16 yl = (__bf16)(qy - (float)yh);
        __bf16 zh = (__bf16)qz; __bf16 zl = (__bf16)(qz - (float)zh);
        float q2h = 0.5f * fmaf(qz, qz, fmaf(qy, qy, qx * qx));
        __bf16 hh = (__bf16)q2h; __bf16 hl = (__bf16)(q2h - (float)hh);
        bf16x8 b0 = {xh, yh, zh, xl, yl, zl, hh, hl};
        bf16x8 b1 = {xh, yh, zh, one, one, xl, yl, zl};
        qfr[t] = kg ? b1 : b0;
        rmin[t] = 3.0e38f;
        asm("" : "+v"(rmin[t]));       // pin min-chain to arch VGPRs
    }
    f32x16 zf = 0.0f;
    asm("" : "+v"(zf));                // pin C operand -> VGPR-form MFMA

    // ---- db segment, single-staged via LDS (A-operand fragments) ----
    const int nchunks = (ndb + 31) >> 5;          // 32-pt chunks
    const int cpseg = (nchunks + SEGS - 1) / SEGS;
    const int c_begin = blockIdx.y * cpseg;
    const int c_end = min(nchunks, c_begin + cpseg);

    // [chunk][kg(2)][row(32)] uint4 -> lane reads sB[c*64 + lane]:
    // 64 lanes x 16B fully linear = conflict-free b128.
    __shared__ uint4 sB[SCH * 64];     // 64 KB; whole segment, one stage

#define MFMA_(A, T) __builtin_amdgcn_mfma_f32_32x32x16_bf16((A), qfr[T], zf, 0, 0, 0)
#define MIN3T(T, D0, D1) do { _Pragma("unroll")                               \
        for (int e = 0; e < 16; ++e)                                          \
            rmin[T][e] = fminf(fminf(rmin[T][e], (D0)[e]), (D1)[e]); } while (0)

    for (int c0 = c_begin; c0 < c_end; c0 += SCH) {
        const int csub = min(SCH, c_end - c0);
        __syncthreads();
        for (int pl = tid; pl < csub * 32; pl += TH) {
            int gp = c0 * 32 + pl;
            float tx = 0.f, ty = 0.f, tz = 0.f, h = 1.0e30f;
            if (gp < ndb) {
                tx = db[gp * 3 + 0]; ty = db[gp * 3 + 1]; tz = db[gp * 3 + 2];
                h = 0.5f * fmaf(tz, tz, fmaf(ty, ty, tx * tx));
            }
            __bf16 xh = (__bf16)tx; __bf16 xl = (__bf16)(tx - (float)xh);
            __bf16 yh = (__bf16)ty; __bf16 yl = (__bf16)(ty - (float)yh);
            __bf16 zh = (__bf16)tz; __bf16 zl = (__bf16)(tz - (float)zh);
            __bf16 hh = (__bf16)h;  __bf16 hl = (__bf16)(h - (float)hh);
            bf16x8 a0 = {xh, yh, zh, xh, yh, zh, one, one};
            bf16x8 a1 = {xl, yl, zl, hh, hl, xl, yl, zl};
            int ch = pl >> 5, cp = pl & 31;
            sB[ch * 64 + cp]      = __builtin_bit_cast(uint4, a0);
            sB[ch * 64 + 32 + cp] = __builtin_bit_cast(uint4, a1);
        }
        __syncthreads();

        // Chunk pairs: 2 ds_read_b128 + 8 MFMA + 64 v_min3, lag-1 ordering:
        // 4 MFMAs issued before the first min3 consumes a result, and the
        // min3 block of tile t sits under the MFMAs of tile t+1.
        int cc = 0;
#pragma unroll 2
        for (; cc + 2 <= csub; cc += 2) {
            bf16x8 aA = __builtin_bit_cast(bf16x8, sB[cc * 64 + lane]);
            bf16x8 aB = __builtin_bit_cast(bf16x8, sB[cc * 64 + 64 + lane]);
            f32x16 dA0 = MFMA_(aA, 0); asm("" : "+v"(dA0));
            f32x16 dB0 = MFMA_(aB, 0); asm("" : "+v"(dB0));
            f32x16 dA1 = MFMA_(aA, 1); asm("" : "+v"(dA1));
            f32x16 dB1 = MFMA_(aB, 1); asm("" : "+v"(dB1));
            MIN3T(0, dA0, dB0);
            f32x16 dA2 = MFMA_(aA, 2); asm("" : "+v"(dA2));
            f32x16 dB2 = MFMA_(aB, 2); asm("" : "+v"(dB2));
            MIN3T(1, dA1, dB1);
            f32x16 dA3 = MFMA_(aA, 3); asm("" : "+v"(dA3));
            f32x16 dB3 = MFMA_(aB, 3); asm("" : "+v"(dB3));
            MIN3T(2, dA2, dB2);
            MIN3T(3, dA3, dB3);
        }
        if (cc < csub) {                           // odd tail chunk
            bf16x8 aA = __builtin_bit_cast(bf16x8, sB[cc * 64 + lane]);
#pragma unroll
            for (int t = 0; t < WT; ++t) {
                f32x16 d0 = MFMA_(aA, t);
                asm("" : "+v"(d0));
                rmin[t] = __builtin_elementwise_min(rmin[t], d0);
            }
        }
    }
#undef MFMA_
#undef MIN3T

    // ---- Epilogue: rows are db -> 15 in-lane mins + 1 shfl_xor(32) ----
#pragma unroll
    for (int t = 0; t < WT; ++t) {
        f32x16 r = rmin[t];
        float v = r[0];
#pragma unroll
        for (int e = 1; e < 16; ++e) v = fminf(v, r[e]);
        v = fminf(v, __shfl_xor(v, 32, 64));       // combine kg halves
        int qi = qtb + t * 32 + rc;
        if (kg == 0 && qi < nq)                    // 32 coalesced stores/tile
            outPart[(size_t)blockIdx.y * nq + qi] = fmaxf(0.0f, v);
    }
}

// Fused reduce: 128 blocks; thread j owns one query: min over SEGS partials,
// sqrt(2*v), block-sum -> partials[b]; poison-aware last block finalizes.
__global__ __launch_bounds__(256) void reduce_kernel(
        const float* __restrict__ partF, const float* __restrict__ partB,
        float* __restrict__ partials, unsigned* __restrict__ counter,
        int n, int m, float* __restrict__ out, int nblocks) {
    const int tid = threadIdx.x;
    const int j = blockIdx.x * 256 + tid;        // flat query id in [0, n+m)
    const bool isF = j < n;
    const float* __restrict__ part = isF ? partF : partB;
    const int qn = isF ? n : m;
    const int qi = isF ? j : j - n;

    float v = 3.0e38f;
#pragma unroll
    for (int s = 0; s < SEGS; ++s)
        v = fminf(v, part[(size_t)s * qn + qi]);
    v = sqrtf(2.0f * fmaxf(0.0f, v));

    for (int off = 32; off > 0; off >>= 1) v += __shfl_down(v, off, 64);
    __shared__ float w[4];
    __shared__ unsigned s_last;
    int lane = tid & 63, wv = tid >> 6;
    if (lane == 0) w[wv] = v;
    __syncthreads();
    if (tid == 0) {
        partials[blockIdx.x] = w[0] + w[1] + w[2] + w[3];
        __threadfence();
        unsigned done = atomicAdd(counter, 1u);
        unsigned nb1 = (unsigned)(nblocks - 1);
        s_last = (done == nb1) || (done == POISON + nb1);
    }
    __syncthreads();
    if (!s_last) return;
    __threadfence();                   // acquire side

    // partials[0..63] = F blocks, [64..127] = B blocks. wave0 sums F, wave1 B.
    float p = 0.0f;
    if (tid < 128)
        p = __uint_as_float(__hip_atomic_load(
                (const unsigned*)&partials[tid],
                __ATOMIC_RELAXED, __HIP_MEMORY_SCOPE_AGENT));
    for (int off = 32; off > 0; off >>= 1) p += __shfl_down(p, off, 64);
    __shared__ float w2[2];
    if (tid == 0)  w2[0] = p;
    if (tid == 64) w2[1] = p;
    __syncthreads();
    if (tid == 0)
        out[0] = 0.5f * (w2[0] / (float)n + w2[1] / (float)m);
}

extern "C" void kernel_launch(void* const* d_in, const int* in_sizes, int n_in,
                              void* d_out, int out_size, void* d_ws, size_t ws_size,
                              hipStream_t stream) {
    const float* pred   = (const float*)d_in[0];
    const float* target = (const float*)d_in[1];
    const int n = in_sizes[0] / 3;   // 16384
    const int m = in_sizes[1] / 3;   // 16384

    float* partF = (float*)d_ws;                  // SEGS*n floats
    float* partB = partF + (size_t)SEGS * n;      // SEGS*m floats
    float* partials = partB + (size_t)SEGS * m;   // 128 floats
    unsigned* counter = (unsigned*)(partials + 128);
    float* out = (float*)d_out;

    int nmax = (n > m) ? n : m;
    int gx = (nmax + QPB - 1) / QPB;         // 16
    dim3 grid(gx, SEGS, 2);                  // 256 blocks -> 1/CU, one round
    chamfer_mfma_kernel<<<grid, TH, 0, stream>>>(pred, n, target, m, partF, partB);

    int nb = (n + m) / 256;                  // 128; F in [0,64), B in [64,128)
    reduce_kernel<<<nb, 256, 0, stream>>>(partF, partB, partials, counter,
                                          n, m, out, nb);
}